// Round 2
// baseline (111.152 us; speedup 1.0000x reference)
//
#include <hip/hip_runtime.h>
#include <math.h>

#define N_V 12288
#define D_F 32
#define N_E 196608
#define KNN 6
#define EPSF 1e-12f

#define SEGS 16
#define JSEG (N_V / SEGS)          // 768 candidate columns per segment
#define SUBTILES (JSEG / 16)       // 48 j-subtiles per segment
#define ROWS_PER_BLOCK 128         // 4 waves x 32 query rows
#define ROW_BLOCKS (N_V / ROWS_PER_BLOCK)  // 96 -> grid 96 x 16 = 1536 blocks (6/CU)
#define NKEEP 5                    // top-5 non-self keys kept per (row, seg)
#define NEGF -3.0e38f

typedef __bf16 bf16x8 __attribute__((ext_vector_type(8)));
typedef float f32x4 __attribute__((ext_vector_type(4)));

static_assert(N_V % ROWS_PER_BLOCK == 0, "");
static_assert(JSEG % ROWS_PER_BLOCK == 0, "");

__device__ __forceinline__ unsigned short f2bf(float f) {
    unsigned u = __builtin_bit_cast(unsigned, f);
    unsigned r = u + 0x7fffu + ((u >> 16) & 1u);   // RNE
    return (unsigned short)(r >> 16);
}

// descending sorted 5-list insert: 1 max + 4 med3
__device__ __forceinline__ void ins5(float s[NKEEP], float nv) {
    float y0 = fmaxf(s[0], nv);
    float y1 = __builtin_amdgcn_fmed3f(s[0], s[1], nv);
    float y2 = __builtin_amdgcn_fmed3f(s[1], s[2], nv);
    float y3 = __builtin_amdgcn_fmed3f(s[2], s[3], nv);
    float y4 = __builtin_amdgcn_fmed3f(s[3], s[4], nv);
    s[0] = y0; s[1] = y1; s[2] = y2; s[3] = y3; s[4] = y4;
}

// ---------- kernel 0: bf16 convert + msq(-0.5*sq), 8 threads/row ----------
__global__ __launch_bounds__(256) void prep_kernel(const float* __restrict__ x,
                                                   unsigned short* __restrict__ xb,
                                                   float* __restrict__ msq) {
    const int gid = blockIdx.x * 256 + threadIdx.x;   // 0..98303
    const int row = gid >> 3;
    const int h = gid & 7;
    float4 p = ((const float4*)(x + (size_t)row * D_F))[h];
    float s = p.x * p.x + p.y * p.y + p.z * p.z + p.w * p.w;
    s += __shfl_xor(s, 1, 64);
    s += __shfl_xor(s, 2, 64);
    s += __shfl_xor(s, 4, 64);
    const unsigned lo = (unsigned)f2bf(p.x) | ((unsigned)f2bf(p.y) << 16);
    const unsigned hi = (unsigned)f2bf(p.z) | ((unsigned)f2bf(p.w) << 16);
    ((uint2*)xb)[gid] = make_uint2(lo, hi);
    if (h == 0) msq[row] = -0.5f * s;
}

// ---------- kernel 1: MFMA gram + per-row top-5 (non-self) keys ----------
// A = candidate rows (j), B = query rows (i). C[m=quad*4+reg][n=l16]:
// lane's query row = rowbase + rt*16 + l16, candidates j = jt + quad*4 + reg.
// acc init = msq[j] => C = dot - 0.5*sq_j (selection key; larger == closer).
// Self-hit (j == row) happens only in the subtile where jt == rowbase+rt*16 —
// a WAVE-UNIFORM condition (1 scalar cmp/subtile); there, 4 cndmasks poison
// the self value to -inf. Single ins5 path everywhere; small VGPR footprint
// so 6 blocks/CU (24 waves/CU) stay resident; 1-deep prefetch hides L2 latency.
__global__ __launch_bounds__(256, 6) void topk_mfma(
    const unsigned short* __restrict__ xb, const float* __restrict__ msq,
    float* __restrict__ cand) {
    const int t = threadIdx.x;
    const int wave = t >> 6;
    const int lane = t & 63;
    const int quad = lane >> 4;
    const int l16 = lane & 15;

    const int rowbase = blockIdx.x * ROWS_PER_BLOCK + wave * 32;
    const int seg = blockIdx.y;
    const int j0 = seg * JSEG;

    // B fragments: query rows, register-resident
    bf16x8 bfrag[2];
#pragma unroll
    for (int rt = 0; rt < 2; ++rt)
        bfrag[rt] = *reinterpret_cast<const bf16x8*>(
            xb + (size_t)(rowbase + rt * 16 + l16) * D_F + quad * 8);

    float tk0[NKEEP], tk1[NKEEP];
#pragma unroll
    for (int k = 0; k < NKEEP; ++k) { tk0[k] = NEGF; tk1[k] = NEGF; }

    const unsigned short* aptr = xb + (size_t)(j0 + l16) * D_F + quad * 8;
    const float* mptr = msq + j0 + quad * 4;

    // lane's self position inside a matching subtile: quad*4+reg == l16
    const int selfreg = (quad == (l16 >> 2)) ? (l16 & 3) : 8;
    const int rb0 = rowbase;
    const int rb1 = rowbase + 16;

    // prefetch subtile 0 (loop prefetches it+1; final over-read lands in ws, unused)
    bf16x8 a_c = *reinterpret_cast<const bf16x8*>(aptr);
    f32x4 m_c = *reinterpret_cast<const f32x4*>(mptr);

    for (int it = 0; it < SUBTILES; ++it) {
        const bf16x8 a_n = *reinterpret_cast<const bf16x8*>(aptr + (it + 1) * (16 * D_F));
        const f32x4 m_n = *reinterpret_cast<const f32x4*>(mptr + (it + 1) * 16);

        f32x4 c0 = __builtin_amdgcn_mfma_f32_16x16x32_bf16(a_c, bfrag[0], m_c, 0, 0, 0);
        f32x4 c1 = __builtin_amdgcn_mfma_f32_16x16x32_bf16(a_c, bfrag[1], m_c, 0, 0, 0);

        const int jt = j0 + (it << 4);
        if (jt == rb0) {   // wave-uniform: this subtile contains rt=0 self diag
            c0[0] = (selfreg == 0) ? NEGF : c0[0];
            c0[1] = (selfreg == 1) ? NEGF : c0[1];
            c0[2] = (selfreg == 2) ? NEGF : c0[2];
            c0[3] = (selfreg == 3) ? NEGF : c0[3];
        }
        if (jt == rb1) {   // wave-uniform: this subtile contains rt=1 self diag
            c1[0] = (selfreg == 0) ? NEGF : c1[0];
            c1[1] = (selfreg == 1) ? NEGF : c1[1];
            c1[2] = (selfreg == 2) ? NEGF : c1[2];
            c1[3] = (selfreg == 3) ? NEGF : c1[3];
        }

        ins5(tk0, c0[0]); ins5(tk0, c0[1]); ins5(tk0, c0[2]); ins5(tk0, c0[3]);
        ins5(tk1, c1[0]); ins5(tk1, c1[1]); ins5(tk1, c1[2]); ins5(tk1, c1[3]);

        a_c = a_n; m_c = m_n;
    }

    // ---- cross-quad merge via shuffles (row's lists live in 4 quads, same l16) ----
#pragma unroll
    for (int rnd = 0; rnd < 2; ++rnd) {
        const int mask = 16 << rnd;
        float b[NKEEP];
#pragma unroll
        for (int k = 0; k < NKEEP; ++k) b[k] = __shfl_xor(tk0[k], mask, 64);
#pragma unroll
        for (int k = 0; k < NKEEP; ++k) ins5(tk0, b[k]);
#pragma unroll
        for (int k = 0; k < NKEEP; ++k) b[k] = __shfl_xor(tk1[k], mask, 64);
#pragma unroll
        for (int k = 0; k < NKEEP; ++k) ins5(tk1, b[k]);
    }

    if (quad == 0) {
        const int g0 = rowbase + l16;
        float* dst0 = cand + ((size_t)g0 * SEGS + seg) * NKEEP;
#pragma unroll
        for (int k = 0; k < NKEEP; ++k) dst0[k] = tk0[k];
        const int g1 = rowbase + 16 + l16;
        float* dst1 = cand + ((size_t)g1 * SEGS + seg) * NKEEP;
#pragma unroll
        for (int k = 0; k < NKEEP; ++k) dst1[k] = tk1[k];
    }
}

// ---------- kernel 2: merge per-segment keys -> v, 4 threads/row ----------
__global__ __launch_bounds__(256) void merge_v(const float* __restrict__ cand,
                                               const float* __restrict__ msq,
                                               float* __restrict__ v,
                                               float* __restrict__ out) {
    const int gid = blockIdx.x * 256 + threadIdx.x;   // 0..49151
    const int row = gid >> 2;
    const int h = gid & 3;
    const float4* c = (const float4*)(cand + (size_t)row * (SEGS * NKEEP));  // 20 x float4
    float mk[NKEEP];
#pragma unroll
    for (int k = 0; k < NKEEP; ++k) mk[k] = NEGF;
#pragma unroll
    for (int s = 0; s < 5; ++s) {
        float4 q = c[h + 4 * s];
        ins5(mk, q.x); ins5(mk, q.y); ins5(mk, q.z); ins5(mk, q.w);
    }
    // merge across the 4 lanes of this row (consecutive lanes, same wave)
#pragma unroll
    for (int rnd = 0; rnd < 2; ++rnd) {
        const int mask = 1 << rnd;
        float b[NKEEP];
#pragma unroll
        for (int k = 0; k < NKEEP; ++k) b[k] = __shfl_xor(mk[k], mask, 64);
#pragma unroll
        for (int k = 0; k < NKEEP; ++k) ins5(mk, b[k]);
    }
    if (h == 0) {
        const float msqi = msq[row];
        float ssum = 0.f;
#pragma unroll
        for (int m = 0; m < NKEEP; ++m) {
            const float d2 = -2.0f * (mk[m] + msqi);   // sq_i - 2*key
            ssum += expf(-sqrtf(fmaxf(d2, EPSF)));
        }
        const float vi = 1.0f - ssum / (float)KNN;
        v[row] = vi;
        out[2 * row] = vi;
        out[2 * row + 1] = 0.0f;
    }
}

// ---------- kernel 3: edge filtration ----------
__global__ __launch_bounds__(256) void edge_kernel(const float* __restrict__ x,
                                                   const int* __restrict__ ei,
                                                   const float* __restrict__ v,
                                                   float* __restrict__ out) {
    int e = blockIdx.x * 256 + threadIdx.x;
    if (e >= N_E) return;
    const int u = ei[e];
    const int w = ei[N_E + e];
    const float4* xu = (const float4*)(x + (size_t)u * D_F);
    const float4* xw = (const float4*)(x + (size_t)w * D_F);
    float a0 = 0.f, a1 = 0.f, a2 = 0.f, a3 = 0.f;
#pragma unroll
    for (int d = 0; d < 8; ++d) {
        float4 p = xu[d], q = xw[d];
        float dx = p.x - q.x, dy = p.y - q.y, dz = p.z - q.z, dw = p.w - q.w;
        a0 += dx * dx; a1 += dy * dy; a2 += dz * dz; a3 += dw * dw;
    }
    const float enorm = sqrtf(fmaxf((a0 + a1) + (a2 + a3), EPSF));
    const float ey = 1.0f - expf(-enorm);
    const float ev = fmaxf(v[u], v[w]);
    out[2 * (N_V + e) + 0] = ev;
    out[2 * (N_V + e) + 1] = ey;
}

extern "C" void kernel_launch(void* const* d_in, const int* in_sizes, int n_in,
                              void* d_out, int out_size, void* d_ws, size_t ws_size,
                              hipStream_t stream) {
    const float* x = (const float*)d_in[0];
    const int* ei = (const int*)d_in[1];
    float* out = (float*)d_out;
    char* ws = (char*)d_ws;

    unsigned short* xb = (unsigned short*)ws;                  // 786432 B
    float* msq = (float*)(ws + 786432);                        // 49152 B
    float* v   = (float*)(ws + 786432 + 49152);                // 49152 B
    float* cand = (float*)(ws + 786432 + 2 * 49152);           // 12288*16*5*4 = 3932160 B

    prep_kernel<<<(N_V * 8) / 256, 256, 0, stream>>>(x, xb, msq);

    dim3 g1(ROW_BLOCKS, SEGS);
    topk_mfma<<<g1, 256, 0, stream>>>(xb, msq, cand);

    merge_v<<<(N_V * 4) / 256, 256, 0, stream>>>(cand, msq, v, out);

    edge_kernel<<<N_E / 256, 256, 0, stream>>>(x, ei, v, out);
}

// Round 3
// 101.602 us; speedup vs baseline: 1.0940x; 1.0940x over previous
//
#include <hip/hip_runtime.h>
#include <math.h>

#define N_V 12288
#define D_F 32
#define N_E 196608
#define KNN 6
#define EPSF 1e-12f

#define SEGS 16
#define JSEG (N_V / SEGS)          // 768 candidate columns per segment
#define SUBTILES (JSEG / 16)       // 48 j-subtiles per segment
#define BLOCK_T 512                // 8 waves
#define ROWS_PER_BLOCK 256         // 8 waves x 32 query rows
#define ROW_BLOCKS (N_V / ROWS_PER_BLOCK)  // 48 -> grid 48 x 16 = 768 blocks (3/CU, 1 round)
#define NKEEP 5                    // top-5 non-self keys kept per (row, seg)
#define NEGF -3.0e38f

#define A_BYTES (JSEG * 64)        // 49152: A tiles, fragment-linear
#define M_OFF A_BYTES              // msq region at 49152
#define LDS_BYTES (A_BYTES + JSEG * 4)  // 52224

typedef __bf16 bf16x8 __attribute__((ext_vector_type(8)));
typedef float f32x4 __attribute__((ext_vector_type(4)));

static_assert(N_V % ROWS_PER_BLOCK == 0, "");
static_assert(SUBTILES % 8 == 0, "");

__device__ __forceinline__ unsigned short f2bf(float f) {
    unsigned u = __builtin_bit_cast(unsigned, f);
    unsigned r = u + 0x7fffu + ((u >> 16) & 1u);   // RNE
    return (unsigned short)(r >> 16);
}

__device__ __forceinline__ float bfu2f(unsigned hw_lo16) {   // low 16 bits -> float
    return __builtin_bit_cast(float, hw_lo16 << 16);
}
__device__ __forceinline__ float bfhi2f(unsigned u) {        // high 16 bits -> float
    return __builtin_bit_cast(float, u & 0xffff0000u);
}

// descending sorted 5-list insert: 1 max + 4 med3
__device__ __forceinline__ void ins5(float s[NKEEP], float nv) {
    float y0 = fmaxf(s[0], nv);
    float y1 = __builtin_amdgcn_fmed3f(s[0], s[1], nv);
    float y2 = __builtin_amdgcn_fmed3f(s[1], s[2], nv);
    float y3 = __builtin_amdgcn_fmed3f(s[2], s[3], nv);
    float y4 = __builtin_amdgcn_fmed3f(s[3], s[4], nv);
    s[0] = y0; s[1] = y1; s[2] = y2; s[3] = y3; s[4] = y4;
}

// ---------- kernel 0: bf16 convert + msq(-0.5*sq), 8 threads/row ----------
__global__ __launch_bounds__(256) void prep_kernel(const float* __restrict__ x,
                                                   unsigned short* __restrict__ xb,
                                                   float* __restrict__ msq) {
    const int gid = blockIdx.x * 256 + threadIdx.x;   // 0..98303
    const int row = gid >> 3;
    const int h = gid & 7;
    float4 p = ((const float4*)(x + (size_t)row * D_F))[h];
    float s = p.x * p.x + p.y * p.y + p.z * p.z + p.w * p.w;
    s += __shfl_xor(s, 1, 64);
    s += __shfl_xor(s, 2, 64);
    s += __shfl_xor(s, 4, 64);
    const unsigned lo = (unsigned)f2bf(p.x) | ((unsigned)f2bf(p.y) << 16);
    const unsigned hi = (unsigned)f2bf(p.z) | ((unsigned)f2bf(p.w) << 16);
    ((uint2*)xb)[gid] = make_uint2(lo, hi);
    if (h == 0) msq[row] = -0.5f * s;
}

// ---------- kernel 1: MFMA gram + per-row top-5 (non-self) keys ----------
// Whole 768-col segment staged in LDS, pre-swizzled fragment-linear:
//   lds[it*1024 + lane*16] = xb row (j0 + it*16 + l16), halfwords quad*8..+8
//   lds[M_OFF + it*64 + quad*16] = msq[j0 + it*16 + quad*4 .. +4]
// Inner loop: ds_read_b128 at base+imm offset (zero addr VALU, no copies,
// no barriers), 2 MFMA, 8x ins5. 8 waves/block, 3 blocks/CU -> 6 waves/SIMD.
__global__ __launch_bounds__(BLOCK_T, 6) void topk_mfma(
    const unsigned short* __restrict__ xb, const float* __restrict__ msq,
    float* __restrict__ cand) {
    __shared__ alignas(16) char lds[LDS_BYTES];
    const int t = threadIdx.x;
    const int wave = t >> 6;
    const int lane = t & 63;
    const int quad = lane >> 4;
    const int l16 = lane & 15;

    const int rowbase = blockIdx.x * ROWS_PER_BLOCK + wave * 32;
    const int seg = blockIdx.y;
    const int j0 = seg * JSEG;

    // ---- stage segment into LDS (each wave: 6 A-subtiles; wave 0: msq) ----
#pragma unroll
    for (int k = 0; k < SUBTILES / 8; ++k) {
        const int it = wave + 8 * k;
        const uint4 val = *((const uint4*)(xb + (size_t)(j0 + it * 16 + l16) * D_F) + quad);
        *((uint4*)(lds + it * 1024) + lane) = val;
    }
    if (wave == 0) {
#pragma unroll
        for (int k = 0; k < 3; ++k) {
            const uint4 val = *((const uint4*)(msq + j0) + k * 64 + lane);
            *((uint4*)(lds + M_OFF + k * 1024) + lane) = val;
        }
    }

    // B fragments: query rows, register-resident (global loads, overlap staging)
    bf16x8 bfrag0 = *reinterpret_cast<const bf16x8*>(
        xb + (size_t)(rowbase + l16) * D_F + quad * 8);
    bf16x8 bfrag1 = *reinterpret_cast<const bf16x8*>(
        xb + (size_t)(rowbase + 16 + l16) * D_F + quad * 8);

    __syncthreads();

    float tk0[NKEEP], tk1[NKEEP];
#pragma unroll
    for (int k = 0; k < NKEEP; ++k) { tk0[k] = NEGF; tk1[k] = NEGF; }

    // lane's self position inside a matching subtile: quad*4+reg == l16
    const int selfreg = (quad == (l16 >> 2)) ? (l16 & 3) : 8;
    const int rb0 = rowbase;
    const int rb1 = rowbase + 16;

    const char* aBase = lds + lane * 16;
    const char* mBase = lds + M_OFF + quad * 16;

#pragma unroll
    for (int it = 0; it < SUBTILES; ++it) {
        const bf16x8 a = *reinterpret_cast<const bf16x8*>(aBase + it * 1024);
        const f32x4 m = *reinterpret_cast<const f32x4*>(mBase + it * 64);

        f32x4 c0 = __builtin_amdgcn_mfma_f32_16x16x32_bf16(a, bfrag0, m, 0, 0, 0);
        f32x4 c1 = __builtin_amdgcn_mfma_f32_16x16x32_bf16(a, bfrag1, m, 0, 0, 0);

        const int jt = j0 + (it << 4);
        if (jt == rb0) {   // wave-uniform: this subtile contains rt=0 self diag
            c0[0] = (selfreg == 0) ? NEGF : c0[0];
            c0[1] = (selfreg == 1) ? NEGF : c0[1];
            c0[2] = (selfreg == 2) ? NEGF : c0[2];
            c0[3] = (selfreg == 3) ? NEGF : c0[3];
        }
        if (jt == rb1) {   // wave-uniform: this subtile contains rt=1 self diag
            c1[0] = (selfreg == 0) ? NEGF : c1[0];
            c1[1] = (selfreg == 1) ? NEGF : c1[1];
            c1[2] = (selfreg == 2) ? NEGF : c1[2];
            c1[3] = (selfreg == 3) ? NEGF : c1[3];
        }

        ins5(tk0, c0[0]); ins5(tk0, c0[1]); ins5(tk0, c0[2]); ins5(tk0, c0[3]);
        ins5(tk1, c1[0]); ins5(tk1, c1[1]); ins5(tk1, c1[2]); ins5(tk1, c1[3]);
    }

    // ---- cross-quad merge via shuffles (row's lists live in 4 quads, same l16) ----
#pragma unroll
    for (int rnd = 0; rnd < 2; ++rnd) {
        const int mask = 16 << rnd;
        float b[NKEEP];
#pragma unroll
        for (int k = 0; k < NKEEP; ++k) b[k] = __shfl_xor(tk0[k], mask, 64);
#pragma unroll
        for (int k = 0; k < NKEEP; ++k) ins5(tk0, b[k]);
#pragma unroll
        for (int k = 0; k < NKEEP; ++k) b[k] = __shfl_xor(tk1[k], mask, 64);
#pragma unroll
        for (int k = 0; k < NKEEP; ++k) ins5(tk1, b[k]);
    }

    if (quad == 0) {
        const int g0 = rowbase + l16;
        float* dst0 = cand + ((size_t)g0 * SEGS + seg) * NKEEP;
#pragma unroll
        for (int k = 0; k < NKEEP; ++k) dst0[k] = tk0[k];
        const int g1 = rowbase + 16 + l16;
        float* dst1 = cand + ((size_t)g1 * SEGS + seg) * NKEEP;
#pragma unroll
        for (int k = 0; k < NKEEP; ++k) dst1[k] = tk1[k];
    }
}

// ---------- kernel 2: merge per-segment keys -> v, 4 threads/row ----------
__global__ __launch_bounds__(256) void merge_v(const float* __restrict__ cand,
                                               const float* __restrict__ msq,
                                               float* __restrict__ v,
                                               float* __restrict__ out) {
    const int gid = blockIdx.x * 256 + threadIdx.x;   // 0..49151
    const int row = gid >> 2;
    const int h = gid & 3;
    const float4* c = (const float4*)(cand + (size_t)row * (SEGS * NKEEP));  // 20 x float4
    float mk[NKEEP];
#pragma unroll
    for (int k = 0; k < NKEEP; ++k) mk[k] = NEGF;
#pragma unroll
    for (int s = 0; s < 5; ++s) {
        float4 q = c[h + 4 * s];
        ins5(mk, q.x); ins5(mk, q.y); ins5(mk, q.z); ins5(mk, q.w);
    }
    // merge across the 4 lanes of this row (consecutive lanes, same wave)
#pragma unroll
    for (int rnd = 0; rnd < 2; ++rnd) {
        const int mask = 1 << rnd;
        float b[NKEEP];
#pragma unroll
        for (int k = 0; k < NKEEP; ++k) b[k] = __shfl_xor(mk[k], mask, 64);
#pragma unroll
        for (int k = 0; k < NKEEP; ++k) ins5(mk, b[k]);
    }
    if (h == 0) {
        const float msqi = msq[row];
        float ssum = 0.f;
#pragma unroll
        for (int m = 0; m < NKEEP; ++m) {
            const float d2 = -2.0f * (mk[m] + msqi);   // sq_i - 2*key
            ssum += expf(-sqrtf(fmaxf(d2, EPSF)));
        }
        const float vi = 1.0f - ssum / (float)KNN;
        v[row] = vi;
        out[2 * row] = vi;
        out[2 * row + 1] = 0.0f;
    }
}

// ---------- kernel 3: edge filtration (bf16 gather: 1 line per row) ----------
__global__ __launch_bounds__(256) void edge_kernel(const unsigned short* __restrict__ xb,
                                                   const int* __restrict__ ei,
                                                   const float* __restrict__ v,
                                                   float* __restrict__ out) {
    int e = blockIdx.x * 256 + threadIdx.x;
    if (e >= N_E) return;
    const int u = ei[e];
    const int w = ei[N_E + e];
    const uint4* xu = (const uint4*)(xb + (size_t)u * D_F);
    const uint4* xw = (const uint4*)(xb + (size_t)w * D_F);
    float acc = 0.f;
#pragma unroll
    for (int d = 0; d < 4; ++d) {
        const uint4 p = xu[d];
        const uint4 q = xw[d];
#pragma unroll
        for (int c = 0; c < 4; ++c) {
            const unsigned pu = (&p.x)[c];
            const unsigned qu = (&q.x)[c];
            const float d0 = bfu2f(pu) - bfu2f(qu);
            const float d1 = bfhi2f(pu) - bfhi2f(qu);
            acc = fmaf(d0, d0, acc);
            acc = fmaf(d1, d1, acc);
        }
    }
    const float enorm = sqrtf(fmaxf(acc, EPSF));
    const float ey = 1.0f - expf(-enorm);
    const float ev = fmaxf(v[u], v[w]);
    out[2 * (N_V + e) + 0] = ev;
    out[2 * (N_V + e) + 1] = ey;
}

extern "C" void kernel_launch(void* const* d_in, const int* in_sizes, int n_in,
                              void* d_out, int out_size, void* d_ws, size_t ws_size,
                              hipStream_t stream) {
    const float* x = (const float*)d_in[0];
    const int* ei = (const int*)d_in[1];
    float* out = (float*)d_out;
    char* ws = (char*)d_ws;

    unsigned short* xb = (unsigned short*)ws;                  // 786432 B
    float* msq = (float*)(ws + 786432);                        // 49152 B
    float* v   = (float*)(ws + 786432 + 49152);                // 49152 B
    float* cand = (float*)(ws + 786432 + 2 * 49152);           // 12288*16*5*4 = 3932160 B

    prep_kernel<<<(N_V * 8) / 256, 256, 0, stream>>>(x, xb, msq);

    dim3 g1(ROW_BLOCKS, SEGS);
    topk_mfma<<<g1, BLOCK_T, 0, stream>>>(xb, msq, cand);

    merge_v<<<(N_V * 4) / 256, 256, 0, stream>>>(cand, msq, v, out);

    edge_kernel<<<N_E / 256, 256, 0, stream>>>(xb, ei, v, out);
}